// Round 6
// baseline (442.012 us; speedup 1.0000x reference)
//
#include <hip/hip_runtime.h>
#include <hip/hip_bf16.h>
#include <cstdint>
#include <cstddef>

// WaveKAN FFN: B=4 S=2048 D=1024 H=4096, M = B*S = 8192.
// layer1: h = mexhat((x-t1)/s1) @ wav_w1^T + silu(x) @ base_w1^T   [M,H]
// layer2: out = mexhat((h-t2)/s2) @ wav_w2^T + silu(h) @ base_w2^T [M,D]
// Branch-GEMMs concatenated along K, INTERLEAVED (k=2i+p: p=0 wav, p=1 silu).
// bf16 MFMA 16x16x32, fp32 accum. Layer-2 activations fused into GEMM1
// epilogue (h never materialized).
// R2: 32x32 MFMA structurally conflicts with BK-major LDS -> 16x16.
// R3: split-K device atomics cost +48us (cross-XCD RMW) -> single-pass.
// R5: hand-hoisted staging/fragment addrs + launch_bounds(256,3):
//     VALUBusy 53->13, VGPR 60, GEMMs ~165/167us.
// R6: XCD-aware swizzle. GEMM2 FETCH was 534MB (3.5x ideal): the 8 column
// blocks sharing an A2 row-tile were round-robined onto 8 different XCDs.
// Remap flat id so XCD c owns M-rows 8c..8c+7 (all column tiles): A-tile
// fetched once per XCD into L2 (2MB<4MB), W stays LLC-resident.

typedef __bf16 bf16x8 __attribute__((ext_vector_type(8)));
typedef float  f32x4  __attribute__((ext_vector_type(4)));
typedef unsigned short u16x8 __attribute__((ext_vector_type(8)));

#define MH_C 0.8673250705840776f   // 2/sqrt(3) * pi^-0.25

__device__ __forceinline__ float mexhat_z(float z) {
    float z2 = z * z;
    return MH_C * (1.0f - z2) * __expf(-0.5f * z2);
}
__device__ __forceinline__ float silu_f(float x) {
    return x / (1.0f + __expf(-x));
}
__device__ __forceinline__ float silu_fast(float x) {
    // x * rcp(1+e^-x): v_rcp_f32 (~1ulp) instead of full fdiv sequence
    return x * __builtin_amdgcn_rcpf(1.0f + __expf(-x));
}
__device__ __forceinline__ unsigned short f2bf(float f) {
    union { __hip_bfloat16 b; unsigned short u; } cv;
    cv.b = __float2bfloat16(f);
    return cv.u;
}

// Fused prep: one dispatch does
//   job 0: W1c [H,2D] ilv <- bf16(wav_w1), bf16(base_w1)      (H*D/4 groups)
//   job 1: W2c [D,2H] ilv <- bf16(wav_w2), bf16(base_w2)      (D*H/4 groups)
//   job 2: A1  [M,2D] ilv <- mexhat((x-t1)/s1), silu(x)       (M*D/4 groups)
template<int D, int H, int M>
__global__ __launch_bounds__(256) void prep_kernel(
        const float* __restrict__ wav_w1, const float* __restrict__ base_w1,
        const float* __restrict__ wav_w2, const float* __restrict__ base_w2,
        const float* __restrict__ x, const float* __restrict__ trans1,
        const float* __restrict__ scale1,
        unsigned short* __restrict__ W1c, unsigned short* __restrict__ W2c,
        unsigned short* __restrict__ A1) {
    constexpr int G1 = H * D / 4;          // cast W1 groups
    constexpr int G2 = D * H / 4;          // cast W2 groups
    int g = blockIdx.x * 256 + threadIdx.x;
    if (g < G1) {
        int idx4 = g * 4;
        int n = idx4 / D, k = idx4 - n * D;
        float4 av = *(const float4*)(wav_w1  + (size_t)n * D + k);
        float4 bv = *(const float4*)(base_w1 + (size_t)n * D + k);
        u16x8 o = { f2bf(av.x), f2bf(bv.x), f2bf(av.y), f2bf(bv.y),
                    f2bf(av.z), f2bf(bv.z), f2bf(av.w), f2bf(bv.w) };
        *(u16x8*)(W1c + (size_t)n * 2 * D + 2 * k) = o;
    } else if (g < G1 + G2) {
        int idx4 = (g - G1) * 4;
        int n = idx4 / H, k = idx4 - n * H;
        float4 av = *(const float4*)(wav_w2  + (size_t)n * H + k);
        float4 bv = *(const float4*)(base_w2 + (size_t)n * H + k);
        u16x8 o = { f2bf(av.x), f2bf(bv.x), f2bf(av.y), f2bf(bv.y),
                    f2bf(av.z), f2bf(bv.z), f2bf(av.w), f2bf(bv.w) };
        *(u16x8*)(W2c + (size_t)n * 2 * H + 2 * k) = o;
    } else {
        int idx4 = (g - G1 - G2) * 4;
        int m = idx4 / D, d = idx4 - m * D;
        float4 xv = *(const float4*)(x + (size_t)m * D + d);
        float4 t  = *(const float4*)(trans1 + d);
        float4 s  = *(const float4*)(scale1 + d);
        u16x8 o = { f2bf(mexhat_z((xv.x - t.x) / s.x)), f2bf(silu_f(xv.x)),
                    f2bf(mexhat_z((xv.y - t.y) / s.y)), f2bf(silu_f(xv.y)),
                    f2bf(mexhat_z((xv.z - t.z) / s.z)), f2bf(silu_f(xv.z)),
                    f2bf(mexhat_z((xv.w - t.w) / s.w)), f2bf(silu_f(xv.w)) };
        *(u16x8*)(A1 + (size_t)m * 2 * D + 2 * d) = o;
    }
}

// C = A @ Bt^T (or fused activation thereof).
// A [M,K] bf16 row-major, Bt [N,K] bf16 row-major.
// 128x128 tile, BK=64, 4 waves 2x2, each wave 64x64 via 4x4
// mfma_f32_16x16x32_bf16. global_load_lds(16B) staging with XOR chunk
// swizzle on the GLOBAL source side; LDS chunk (row,j) holds global
// k-chunk j^(row&7): per 16-lane quarter 8 bank-groups x 2 lanes = free.
// Staging pointers / fragment LDS offsets hoisted out of the K-loop.
// XCD swizzle (LG2GX = log2 gridDim.x, gridDim.y must be 64): flat id b,
// xcd = b&7 (round-robin dispatch), bx = (b>>3) & (GX-1),
// by = xcd*8 + (b>>3)>>LG2GX  -> XCD c owns M-rows 8c..8c+7, so each
// A row-tile is HBM-fetched once (by one XCD) and L2-reused by all
// column blocks; W cycles through LLC.
// EPI=0: plain fp32 stores.  EPI=1: layer-2 acts -> A2 [M,2N] bf16 ilv.
template<int EPI, int LG2GX>
__global__ __launch_bounds__(256, 3)
void gemm_bt_kernel(const unsigned short* __restrict__ A,
                    const unsigned short* __restrict__ Bt,
                    float* __restrict__ C,
                    unsigned short* __restrict__ A2,
                    const float* __restrict__ trans,
                    const float* __restrict__ scale,
                    int N, int K) {
    __shared__ __align__(16) unsigned short sA[128 * 64];
    __shared__ __align__(16) unsigned short sB[128 * 64];

    const int tid  = threadIdx.x;
    const int lane = tid & 63;
    const int wv   = tid >> 6;
    const int wm   = wv >> 1;          // wave row 0..1 (64 rows each)
    const int wn   = wv & 1;           // wave col 0..1
    const int quad = lane >> 4;        // 0..3
    const int l15  = lane & 15;

    // ---- XCD-aware tile assignment ----
    const unsigned b   = blockIdx.y * gridDim.x + blockIdx.x;
    const unsigned xcd = b & 7;
    const unsigned j   = b >> 3;
    const int bx = j & ((1u << LG2GX) - 1);
    const int by = (int)(xcd * 8 + (j >> LG2GX));
    const int rowBase = by * 128;
    const int colBase = bx * 128;

    // ---- hoisted staging addresses (loop-invariant except +k0) ----
    const unsigned short* gA[4];
    const unsigned short* gB[4];
    unsigned short* lA[4];
    unsigned short* lB[4];
    #pragma unroll
    for (int r = 0; r < 4; ++r) {
        int c  = r * 256 + wv * 64 + lane;          // LDS chunk id
        int m  = c >> 3;                            // tile row
        int gk = ((c & 7) ^ (m & 7)) * 8;           // swizzled k offset (elems)
        gA[r] = A  + (size_t)(rowBase + m) * K + gk;
        gB[r] = Bt + (size_t)(colBase + m) * K + gk;
        lA[r] = sA + (size_t)(r * 256 + wv * 64) * 8;   // wave-uniform base
        lB[r] = sB + (size_t)(r * 256 + wv * 64) * 8;
    }

    // ---- hoisted fragment LDS offsets (elements) ----
    int offA[2][4], offB[2][4];
    #pragma unroll
    for (int kk = 0; kk < 2; ++kk) {
        int kcb = kk * 4 + quad;
        #pragma unroll
        for (int i = 0; i < 4; ++i) {
            int m = wm * 64 + i * 16 + l15;
            offA[kk][i] = (m * 8 + (kcb ^ (m & 7))) * 8;
            int n = wn * 64 + i * 16 + l15;
            offB[kk][i] = (n * 8 + (kcb ^ (n & 7))) * 8;
        }
    }

    f32x4 acc[4][4] = {};

    for (int k0 = 0; k0 < K; k0 += 64) {
        #pragma unroll
        for (int r = 0; r < 4; ++r) {
            __builtin_amdgcn_global_load_lds(
                (const __attribute__((address_space(1))) void*)(gA[r] + k0),
                (__attribute__((address_space(3))) void*)lA[r], 16, 0, 0);
            __builtin_amdgcn_global_load_lds(
                (const __attribute__((address_space(1))) void*)(gB[r] + k0),
                (__attribute__((address_space(3))) void*)lB[r], 16, 0, 0);
        }
        __syncthreads();

        #pragma unroll
        for (int kk = 0; kk < 2; ++kk) {
            bf16x8 af[4], bfr[4];
            #pragma unroll
            for (int i = 0; i < 4; ++i) {
                af[i]  = *(const bf16x8*)(sA + offA[kk][i]);
                bfr[i] = *(const bf16x8*)(sB + offB[kk][i]);
            }
            #pragma unroll
            for (int i = 0; i < 4; ++i)
                #pragma unroll
                for (int j2 = 0; j2 < 4; ++j2)
                    acc[i][j2] = __builtin_amdgcn_mfma_f32_16x16x32_bf16(
                        af[i], bfr[j2], acc[i][j2], 0, 0, 0);
        }
        __syncthreads();
    }

    // ---- epilogue: D[row=(lane>>4)*4+r][col=lane&15] (m89-verified) ----
    #pragma unroll
    for (int jj = 0; jj < 4; ++jj) {
        const int col = colBase + wn * 64 + jj * 16 + l15;
        float t = 0.f, rsc = 1.f;
        if (EPI == 1) { t = trans[col]; rsc = __builtin_amdgcn_rcpf(scale[col]); }
        #pragma unroll
        for (int i = 0; i < 4; ++i) {
            const int row0 = rowBase + wm * 64 + i * 16 + quad * 4;
            #pragma unroll
            for (int r = 0; r < 4; ++r) {
                float h = acc[i][jj][r];
                if (EPI == 0) {
                    C[(size_t)(row0 + r) * N + col] = h;
                } else {
                    float z = (h - t) * rsc;
                    unsigned int u = (unsigned int)f2bf(mexhat_z(z))
                                   | ((unsigned int)f2bf(silu_fast(h)) << 16);
                    *(unsigned int*)(A2 + (size_t)(row0 + r) * (size_t)(2 * N)
                                        + 2 * col) = u;
                }
            }
        }
    }
}

extern "C" void kernel_launch(void* const* d_in, const int* in_sizes, int n_in,
                              void* d_out, int out_size, void* d_ws, size_t ws_size,
                              hipStream_t stream) {
    (void)in_sizes; (void)n_in; (void)out_size; (void)ws_size;
    const float* x       = (const float*)d_in[0];
    const float* scale1  = (const float*)d_in[1];
    const float* trans1  = (const float*)d_in[2];
    const float* wav_w1  = (const float*)d_in[3];
    const float* base_w1 = (const float*)d_in[4];
    const float* scale2  = (const float*)d_in[5];
    const float* trans2  = (const float*)d_in[6];
    const float* wav_w2  = (const float*)d_in[7];
    const float* base_w2 = (const float*)d_in[8];
    float* out = (float*)d_out;

    const int M = 8192, D = 1024, H = 4096;

    // workspace layout: W1c 16M | W2c 16M | A1 32M | A2 128M = 192 MiB
    unsigned short* W1c = (unsigned short*)d_ws;                 // [H, 2D] ilv
    unsigned short* W2c = W1c + (size_t)H * 2 * D;               // [D, 2H] ilv
    unsigned short* A1  = W2c + (size_t)D * 2 * H;               // [M, 2D] ilv
    unsigned short* A2  = A1  + (size_t)M * 2 * D;               // [M, 2H] ilv

    // fused prep: cast W1, cast W2, layer-1 activations (one dispatch)
    {
        const int groups = H * D / 4 + D * H / 4 + M * D / 4;   // 4,194,304
        prep_kernel<D, H, M><<<groups / 256, 256, 0, stream>>>(
            wav_w1, base_w1, wav_w2, base_w2, x, trans1, scale1, W1c, W2c, A1);
    }
    // GEMM1: [M,2D] @ [H,2D]^T -> fused layer-2 activations -> A2 [M,2H]
    {
        dim3 grid(H / 128, M / 128);   // (32, 64), LG2GX=5
        gemm_bt_kernel<1, 5><<<grid, 256, 0, stream>>>(A1, W1c, nullptr, A2,
                                                       trans2, scale2, H, 2 * D);
    }
    // GEMM2: [M,2H] @ [D,2H]^T -> out fp32 [M,D]
    {
        dim3 grid(D / 128, M / 128);   // (8, 64), LG2GX=3
        gemm_bt_kernel<0, 3><<<grid, 256, 0, stream>>>(A2, W2c, out, nullptr,
                                                       nullptr, nullptr, D, 2 * H);
    }
}